// Round 1
// 366.899 us; speedup vs baseline: 1.0164x; 1.0164x over previous
//
#include <hip/hip_runtime.h>

// ---------------------------------------------------------------------------
// MAF forward log-prob, fully fused. D=45, H=256, NB=6, L=2, K=8, M=23.
// R4: hidden units permuted into sorted-degree order so every MADE mask is a
// K-prefix; each GEMM reads only the needed K-tile prefix per col-group
// (57% of prior MFMA work). Waves execute 2 balanced (cg,half,KT) items from
// compile-time schedules. pbuf re-laid per-feature (24-elem rows, skewed) so
// the spline reads params as 3x ds_read_b128; spline rows fixed per thread so
// log-det accumulates in a register (one LDS atomic at end). 512 thr/WG,
// ~79 KiB LDS, 2 WGs/CU.
// ---------------------------------------------------------------------------

typedef __bf16 bf16;
typedef __bf16 bf16x8 __attribute__((ext_vector_type(8)));
typedef float  f32x16 __attribute__((ext_vector_type(16)));

#define TAILF  13.815510557964274f      /* -log(1e-6) */
#define LOGZ   41.352233994210265f      /* 0.5*45*log(2*pi) */

// ---------------- workspace layout (bytes) ----------------
#define WS_W0M   0            /* bf16 [6][8 cg][4 kt][512]   196608 */
#define WS_WHM   196608       /* bf16 [12][8 cg][16 kt][512] 1572864 */
#define WS_WFM   1769472      /* bf16 [30][7 cg][16 kt][512] 3440640 */
#define WS_BEFF  5210112      /* f32  [6][256]   6144 */
#define WS_BFP   5216256      /* f32  [30][224]  26880 */
#define WS_WCC   5243136      /* f32  [6][256]   6144 */
#define WS_BHP   5249280      /* f32  [12][256]  12288 */
#define WS_NEED  5261568

#define N_W0  (6*256*64)        /* 98304   */
#define N_WH  (6*2*256*256)     /* 786432  */
#define N_WF  (6*5*224*256)     /* 1720320 */
#define N_PREP (N_W0 + N_WH + N_WF)

// ---- sorted-degree permutation of hidden units ----
// orig degree-1 of unit k is k%44.  Sorted position s -> degree-1 s_deg(s),
// original index s_orig(s).  Degrees 0..35 have 6 copies, 36..43 have 5.
__device__ __forceinline__ int s_deg(int s) {
    return (s < 216) ? (s / 6) : (36 + (s - 216) / 5);
}
__device__ __forceinline__ int s_orig(int s) {
    int d, rk;
    if (s < 216) { d = s / 6; rk = s - d * 6; }
    else { int u = s - 216; d = 36 + u / 5; rk = u - (u / 5) * 5; }
    return d + 44 * rk;
}

// ---------------- merged prep kernel (mask + permute + cast + pack) --------
__global__ void prep_all(const float* __restrict__ W0, const float* __restrict__ b0,
                         const float* __restrict__ Wc, const float* __restrict__ bc,
                         const float* __restrict__ Wh, const float* __restrict__ Wf,
                         const float* __restrict__ bfv, const float* __restrict__ bh,
                         bf16* __restrict__ W0m, bf16* __restrict__ Whm,
                         bf16* __restrict__ Wfm,
                         float* __restrict__ beff, float* __restrict__ bfp,
                         float* __restrict__ Wcc, float* __restrict__ bhp)
{
    int idx = blockIdx.x * 256 + threadIdx.x;
    if (idx < N_W0) {
        int j = idx & 7, lane = (idx >> 3) & 63, chunk = idx >> 9;
        int kt = chunk & 3, cg = (chunk >> 2) & 7, b = chunk >> 5;
        int col = cg * 32 + (lane & 31);               // sorted hidden pos
        int k   = kt * 16 + (lane >> 5) * 8 + j;
        int o   = s_orig(col);
        float v = 0.f;
        if (k < 45 && s_deg(col) >= k)                 // m0: deg_h >= k+1
            v = W0[(b * 256 + o) * 45 + k];
        W0m[idx] = (bf16)v;
        if (k == 0) {
            beff[b * 256 + col] = b0[b * 256 + o] + bc[b * 256 + o];
            Wcc[b * 256 + col]  = Wc[b * 256 + o];
        }
    } else if (idx < N_W0 + N_WH) {
        int id = idx - N_W0;
        int j = id & 7, lane = (id >> 3) & 63, chunk = id >> 9;
        int kt = chunk & 15, cg = (chunk >> 4) & 7, bl = chunk >> 7;  // bl=b*2+l
        int col = cg * 32 + (lane & 31);
        int k   = kt * 16 + (lane >> 5) * 8 + j;
        int oc  = s_orig(col), ok = s_orig(k);
        float v = (s_deg(col) >= s_deg(k)) ? Wh[bl * 65536 + oc * 256 + ok] : 0.f;
        Whm[id] = (bf16)v;
        if (k == 0)
            bhp[bl * 256 + col] = bh[bl * 256 + oc];
    } else if (idx < N_PREP) {
        int id = idx - (N_W0 + N_WH);
        int j = id & 7, lane = (id >> 3) & 63, chunk = id >> 9;
        int kt = chunk & 15, t2 = chunk >> 4;
        int cg = t2 % 7, bg = t2 / 7;                  // bg = b*5+g
        int b  = bg / 5, g = bg - 5 * b;
        int col = cg * 32 + (lane & 31);               // 0..223 (param col)
        int k   = kt * 16 + (lane >> 5) * 8 + j;
        int ok  = s_orig(k);
        int f   = 9 * g + col / 23;
        int m   = col - (col / 23) * 23;
        bool valid = (col < 207);
        float v = 0.f;
        if (valid && (f > s_deg(k)))                   // mf strict
            v = Wf[(b * 1035 + f * 23 + m) * 256 + ok];
        Wfm[id] = (bf16)v;
        if (k == 0)
            bfp[bg * 224 + col] = valid ? bfv[b * 1035 + f * 23 + m] : 0.f;
    }
}

// ---------------- fused main kernel ----------------
// LDS (dynamic, 81040 B -> 2 blocks/CU):
#define SO_ZF    0        /* float [64][46]          11776 */
#define SO_ZB    11776    /* bf16  [64][56]           7168 */
#define SO_HIDA  18944    /* bf16  [64][264]         33792 */
#define SO_PBUF  52736    /* bf16  9 x 1544 (fl-major, 24/row + 8 skew) 27792 */
#define SO_COND  80528    /* float [64] */
#define SO_LD    80784    /* float [64] */
#define SMEM_BYTES 81040

#define PBF 1544          /* elements per feature slab: 64*24 + 8 skew */

// Balanced wave schedules: per wave, two items (cg, half, kt-prefix).
// Encoded e = (kt<<8)|(half<<5)|cg; two items packed in one u32. cg=31 idle.
#define E2(c0,h0,k0,c1,h1,k1) \
    ( (unsigned)(((k0)<<8)|((h0)<<5)|(c0)) | ((unsigned)(((k1)<<8)|((h1)<<5)|(c1))<<16) )

__constant__ unsigned SCHED_IN[8] = {      // per-cg KT [1,1,1,2,2,2,3,3]
    E2(6,0,3, 0,0,1), E2(6,1,3, 0,1,1), E2(7,0,3, 1,0,1), E2(7,1,3, 1,1,1),
    E2(3,0,2, 2,0,1), E2(3,1,2, 2,1,1), E2(4,0,2, 5,0,2), E2(4,1,2, 5,1,2)
};
__constant__ unsigned SCHED_HID[8] = {     // per-cg KT [3,5,6,9,11,12,15,16]
    E2(7,0,16, 0,0,3), E2(7,1,16, 0,1,3), E2(6,0,15, 1,0,5), E2(6,1,15, 1,1,5),
    E2(5,0,12, 2,0,6), E2(5,1,12, 2,1,6), E2(4,0,11, 3,0,9), E2(4,1,11, 3,1,9)
};
__constant__ unsigned SCHED_OUT[5][8] = {
  { E2(4,0,3, 0,0,1),  E2(4,1,3, 0,1,1),  E2(5,0,3, 1,0,1),  E2(5,1,3, 1,1,1),
    E2(6,0,3, 31,0,0), E2(6,1,3, 31,0,0), E2(2,0,2, 2,1,2),  E2(3,0,2, 3,1,2) },
  { E2(5,0,7, 0,0,4),  E2(5,1,7, 0,1,4),  E2(6,0,7, 31,0,0), E2(6,1,7, 31,0,0),
    E2(3,0,6, 1,0,5),  E2(3,1,6, 1,1,5),  E2(4,0,6, 2,0,5),  E2(4,1,6, 2,1,5) },
  { E2(5,0,10, 0,0,8), E2(5,1,10, 0,1,8), E2(6,0,10, 1,0,8), E2(6,1,10, 1,1,8),
    E2(2,0,9, 2,1,9),  E2(3,0,9, 3,1,9),  E2(4,0,9, 31,0,0), E2(4,1,9, 31,0,0) },
  { E2(5,0,14, 0,0,11),E2(5,1,14, 0,1,11),E2(6,0,14, 31,0,0),E2(6,1,14, 31,0,0),
    E2(4,0,13, 1,0,11),E2(4,1,13, 1,1,11),E2(2,0,12, 2,1,12),E2(3,0,12, 3,1,12) },
  { E2(3,0,16, 0,0,14),E2(3,1,16, 0,1,14),E2(4,0,16, 1,0,15),E2(4,1,16, 1,1,15),
    E2(5,0,16, 2,0,15),E2(5,1,16, 2,1,15),E2(6,0,16, 31,0,0),E2(6,1,16, 31,0,0) }
};

// Epilogue for one 32x32 accumulator. C/D: col=lane&31, row=(r&3)+8*(r>>2)+4*(lane>>5).
// MODE 0: +bias+cond*wcol -> hidA; MODE 1: +bias, relu -> hidA;
// MODE 2: +bias -> pbuf (per-feature slab layout).
template<int MODE>
__device__ __forceinline__ void epi32(const f32x16& acc, int cg, int hf,
    const float* __restrict__ bias, const float* __restrict__ wcol,
    const float* condl, bf16* dst, int l31, int kh8)
{
    const int col = cg * 32 + l31;
    if (MODE == 2 && col >= 207) return;
    const float bv = bias[col];
    const int rb = (kh8 >> 1) + hf * 32;    // 4*(lane>>5) + half*32
    if (MODE == 2) {
        const int fl = col / 23, m = col - fl * 23;
        bf16* dp = dst + fl * PBF + m;
        #pragma unroll
        for (int r = 0; r < 16; ++r) {
            int row = (r & 3) + 8 * (r >> 2) + rb;
            dp[row * 24] = (bf16)(acc[r] + bv);
        }
    } else {
        const float wcv = (MODE == 0) ? wcol[col] : 0.f;
        #pragma unroll
        for (int r = 0; r < 16; ++r) {
            int row = (r & 3) + 8 * (r >> 2) + rb;
            float v = acc[r] + bv;
            if (MODE == 0) v += condl[row] * wcv;
            if (MODE == 1) v = fmaxf(v, 0.f);
            dst[row * 264 + col] = (bf16)v;
        }
    }
}

// GEMM: per wave, two scheduled items; each accumulates a 32x32 tile over its
// K-tile prefix. B streams coalesced from packed chunks (lane*16B per 1KB
// chunk); A frag [row=lane&31][k=(lane>>5)*8+j] from LDS.
template<int KTFULL, int MODE>
__device__ __forceinline__ void gemm32(
    const bf16* Asrc, const int lda,
    const bf16* __restrict__ Wp,
    const float* __restrict__ bias, const float* __restrict__ wcol,
    const float* condl, bf16* dst,
    const unsigned* __restrict__ sched,
    int w, int lane, bool preEpiSync)
{
    const int l31 = lane & 31;
    const int kh8 = (lane >> 5) * 8;
    const unsigned se = sched[__builtin_amdgcn_readfirstlane(w)];
    const int cg0 = se & 31,         hf0 = (se >> 5) & 1,  kt0 = (se >> 8) & 31;
    const int cg1 = (se >> 16) & 31, hf1 = (se >> 21) & 1, kt1 = (se >> 24) & 31;

    f32x16 acc0 = {}, acc1 = {};
    {
        const bf16* Bp = Wp + (size_t)cg0 * (KTFULL * 512) + lane * 8;
        const bf16* Ap = Asrc + (hf0 * 32 + l31) * lda + kh8;
        #pragma unroll 1
        for (int kb = 0; kb < kt0; kb += 4) {
            bf16x8 bq[4], aq[4];
            #pragma unroll
            for (int c = 0; c < 4; ++c) if (kb + c < kt0) {
                bq[c] = *reinterpret_cast<const bf16x8*>(Bp + (kb + c) * 512);
                aq[c] = *reinterpret_cast<const bf16x8*>(Ap + (kb + c) * 16);
            }
            #pragma unroll
            for (int c = 0; c < 4; ++c) if (kb + c < kt0)
                acc0 = __builtin_amdgcn_mfma_f32_32x32x16_bf16(aq[c], bq[c], acc0, 0, 0, 0);
        }
    }
    {
        const bf16* Bp = Wp + (size_t)cg1 * (KTFULL * 512) + lane * 8;
        const bf16* Ap = Asrc + (hf1 * 32 + l31) * lda + kh8;
        #pragma unroll 1
        for (int kb = 0; kb < kt1; kb += 4) {
            bf16x8 bq[4], aq[4];
            #pragma unroll
            for (int c = 0; c < 4; ++c) if (kb + c < kt1) {
                bq[c] = *reinterpret_cast<const bf16x8*>(Bp + (kb + c) * 512);
                aq[c] = *reinterpret_cast<const bf16x8*>(Ap + (kb + c) * 16);
            }
            #pragma unroll
            for (int c = 0; c < 4; ++c) if (kb + c < kt1)
                acc1 = __builtin_amdgcn_mfma_f32_32x32x16_bf16(aq[c], bq[c], acc1, 0, 0, 0);
        }
    }

    if (preEpiSync) __syncthreads();   // in-place layers: all A reads done

    if (cg0 != 31) epi32<MODE>(acc0, cg0, hf0, bias, wcol, condl, dst, l31, kh8);
    if (cg1 != 31) epi32<MODE>(acc1, cg1, hf1, bias, wcol, condl, dst, l31, kh8);
    __syncthreads();
}

// RQ spline for 9 features starting at fb. Task map: fl = task>>6 (wave-
// uniform), r = task&63 -> fixed row per thread; log-det accumulates in reg.
__device__ __forceinline__ void do_spline9(int fb, float* zf, bf16* zb,
                                           const bf16* pbuf, int t, float& lad_acc)
{
    #pragma unroll 1
    for (int task = t; task < 576; task += 512) {
        int fl = task >> 6, r = task & 63;
        const bf16* pp = pbuf + fl * PBF + r * 24;
        bf16x8 q0 = *reinterpret_cast<const bf16x8*>(pp);
        bf16x8 q1 = *reinterpret_cast<const bf16x8*>(pp + 8);
        bf16x8 q2 = *reinterpret_cast<const bf16x8*>(pp + 16);
        float P[23];
        #pragma unroll
        for (int m = 0; m < 8; ++m) P[m]      = (float)q0[m];
        #pragma unroll
        for (int m = 0; m < 8; ++m) P[8 + m]  = (float)q1[m];
        #pragma unroll
        for (int m = 0; m < 7; ++m) P[16 + m] = (float)q2[m];

        float xin = zf[r * 46 + fb + fl];
        float xc  = fminf(fmaxf(xin, -TAILF), TAILF);
        bool inside = (xin >= -TAILF) && (xin <= TAILF);

        float mw = P[0];
        #pragma unroll
        for (int i = 1; i < 8; ++i) mw = fmaxf(mw, P[i]);
        float ew[8], sw = 0.f;
        #pragma unroll
        for (int i = 0; i < 8; ++i) { ew[i] = __expf((P[i] - mw) * 0.0625f); sw += ew[i]; }
        float rws = 0.992f / sw;
        float cw[9]; cw[0] = -TAILF;
        #pragma unroll
        for (int i = 0; i < 8; ++i)
            cw[i + 1] = cw[i] + 2.f * TAILF * (1e-3f + ew[i] * rws);
        cw[8] = TAILF;
        float wb[8];
        #pragma unroll
        for (int i = 0; i < 8; ++i) wb[i] = cw[i + 1] - cw[i];

        float mh = P[8];
        #pragma unroll
        for (int i = 1; i < 8; ++i) mh = fmaxf(mh, P[8 + i]);
        float eh[8], sh = 0.f;
        #pragma unroll
        for (int i = 0; i < 8; ++i) { eh[i] = __expf((P[8 + i] - mh) * 0.0625f); sh += eh[i]; }
        float rhs = 0.992f / sh;
        float ch[9]; ch[0] = -TAILF;
        #pragma unroll
        for (int i = 0; i < 8; ++i)
            ch[i + 1] = ch[i] + 2.f * TAILF * (1e-3f + eh[i] * rhs);
        ch[8] = TAILF;
        float hb[8];
        #pragma unroll
        for (int i = 0; i < 8; ++i) hb[i] = ch[i + 1] - ch[i];

        float dd[9];
        dd[0] = 1.0f; dd[8] = 1.0f;
        #pragma unroll
        for (int i = 1; i < 8; ++i)
            dd[i] = 1e-3f + __logf(1.f + __expf(P[15 + i]));

        float icw = cw[0], ich = ch[0], ibw = wb[0], ibh = hb[0];
        float id0 = dd[0], id1 = dd[1];
        #pragma unroll
        for (int i = 1; i < 8; ++i) {
            bool ge = xc >= cw[i];
            icw = ge ? cw[i] : icw;  ich = ge ? ch[i] : ich;
            ibw = ge ? wb[i] : ibw;  ibh = ge ? hb[i] : ibh;
            id0 = ge ? dd[i] : id0;  id1 = ge ? dd[i + 1] : id1;
        }

        float th  = (xc - icw) / ibw;
        float th1 = th * (1.f - th);
        float dl  = ibh / ibw;
        float den = dl + (id0 + id1 - 2.f * dl) * th1;
        float yy  = ich + ibh * (dl * th * th + id0 * th1) / den;
        float num = dl * dl * (id1 * th * th + 2.f * dl * th1
                               + id0 * (1.f - th) * (1.f - th));
        float lad = __logf(num) - 2.f * __logf(den);

        if (inside) {
            zf[r * 46 + fb + fl] = yy;
            zb[r * 56 + fb + fl] = (bf16)yy;
        }
        lad_acc += inside ? lad : 0.f;
    }
}

__global__ __launch_bounds__(512, 4) void maf_main(
    const float* __restrict__ x, const float* __restrict__ cond,
    const bf16* __restrict__ W0m, const bf16* __restrict__ Whm,
    const bf16* __restrict__ Wfm,
    const float* __restrict__ beff, const float* __restrict__ bfp,
    const float* __restrict__ Wcc, const float* __restrict__ bhp,
    float* __restrict__ out, int B)
{
    extern __shared__ char smem[];
    float* zf    = (float*)(smem + SO_ZF);
    bf16*  zb    = (bf16*)(smem + SO_ZB);
    bf16*  hidA  = (bf16*)(smem + SO_HIDA);
    bf16*  pbuf  = (bf16*)(smem + SO_PBUF);
    float* condl = (float*)(smem + SO_COND);
    float* ldl   = (float*)(smem + SO_LD);

    const int t    = threadIdx.x;
    const int r0   = blockIdx.x * 64;
    const int w    = t >> 6;
    const int lane = t & 63;

    for (int i = t; i < 64 * 11; i += 512) {
        int r = i / 11, c = i - (i / 11) * 11;
        zb[r * 56 + 45 + c] = (bf16)0.f;
    }
    for (int i = t; i < 64 * 45; i += 512) {
        int r = i / 45, f = i - (i / 45) * 45;
        float v = (r0 + r < B) ? x[(size_t)(r0 + r) * 45 + f] : 0.f;
        zf[r * 46 + f] = v;
        zb[r * 56 + f] = (bf16)v;
    }
    if (t < 64) {
        condl[t] = (r0 + t < B) ? cond[r0 + t] : 0.f;
        ldl[t]   = 0.f;
    }
    __syncthreads();

    float lad_acc = 0.f;

    #pragma unroll 1
    for (int b = 0; b < 6; ++b) {
        // input MADE layer (K-prefix <= 48 of padded 64), +cond*Wc + (b0+bc)
        gemm32<4, 0>(zb, 56, W0m + b * 16384,
                     beff + b * 256, Wcc + b * 256, condl,
                     hidA, SCHED_IN, w, lane, false);
        // 2 hidden layers, relu, in-place
        #pragma unroll 1
        for (int l = 0; l < 2; ++l)
            gemm32<16, 1>(hidA, 264, Whm + (b * 2 + l) * 65536,
                          bhp + (b * 2 + l) * 256, nullptr, condl,
                          hidA, SCHED_HID, w, lane, true);
        // params: 5 groups x 9 features (207 real cols of 224)
        #pragma unroll 1
        for (int g = 0; g < 5; ++g) {
            gemm32<16, 2>(hidA, 264, Wfm + (size_t)(b * 5 + g) * 57344,
                          bfp + (b * 5 + g) * 224, nullptr, condl,
                          pbuf, SCHED_OUT[g], w, lane, false);
            do_spline9(g * 9, zf, zb, pbuf, t, lad_acc);
            __syncthreads();
        }
    }

    atomicAdd(&ldl[t & 63], lad_acc);
    __syncthreads();

    if (t < 64 && r0 + t < B) {
        float s = 0.f;
        #pragma unroll
        for (int f = 0; f < 45; ++f) { float v = zf[t * 46 + f]; s += v * v; }
        out[r0 + t] = -0.5f * s - LOGZ + ldl[t];
    }
}

// ---------------- host entry ----------------
extern "C" void kernel_launch(void* const* d_in, const int* in_sizes, int n_in,
                              void* d_out, int out_size, void* d_ws, size_t ws_size,
                              hipStream_t stream)
{
    const float* x    = (const float*)d_in[0];
    const float* cond = (const float*)d_in[1];
    const float* W0   = (const float*)d_in[2];
    const float* b0   = (const float*)d_in[3];
    const float* Wc   = (const float*)d_in[4];
    const float* bc   = (const float*)d_in[5];
    const float* Wh   = (const float*)d_in[6];
    const float* bh   = (const float*)d_in[7];
    const float* Wf   = (const float*)d_in[8];
    const float* bfv  = (const float*)d_in[9];
    float* out = (float*)d_out;

    const int B = in_sizes[0] / 45;
    if (ws_size < (size_t)WS_NEED) return;   // fail loudly

    char* ws = (char*)d_ws;
    bf16*  W0m  = (bf16*)(ws + WS_W0M);
    bf16*  Whm  = (bf16*)(ws + WS_WHM);
    bf16*  Wfm  = (bf16*)(ws + WS_WFM);
    float* beff = (float*)(ws + WS_BEFF);
    float* bfp  = (float*)(ws + WS_BFP);
    float* Wcc  = (float*)(ws + WS_WCC);
    float* bhp  = (float*)(ws + WS_BHP);

    prep_all<<<(N_PREP + 255) / 256, 256, 0, stream>>>(
        W0, b0, Wc, bc, Wh, Wf, bfv, bh, W0m, Whm, Wfm, beff, bfp, Wcc, bhp);

    (void)hipFuncSetAttribute((const void*)maf_main,
                              hipFuncAttributeMaxDynamicSharedMemorySize,
                              SMEM_BYTES);

    const int nwg = (B + 63) / 64;
    maf_main<<<nwg, 512, SMEM_BYTES, stream>>>(
        x, cond, W0m, Whm, Wfm, beff, bfp, Wcc, bhp, out, B);
}

// Round 2
// 325.595 us; speedup vs baseline: 1.1453x; 1.1269x over previous
//
#include <hip/hip_runtime.h>

// ---------------------------------------------------------------------------
// MAF forward log-prob, fully fused. D=45, H=256, NB=6, L=2, K=8, M=23.
// R5: one col-group per wave with BOTH row-halves (2 accs share each 1KB
// B-chunk -> B traffic -35%, 2 MFMAs amortize each global load). Inner loop
// statically pipelined: kt padded to x4 (zero chunks are free), switch(nq)
// emits straight-line code with 2-quad B preload (8 loads in flight) and
// distance-1-quad prefetch in explicit ping-pong regs. Sorted-degree
// permutation keeps every MADE mask a K-prefix. 512 thr/WG, ~79 KiB LDS,
// 2 WGs/CU.
// ---------------------------------------------------------------------------

typedef __bf16 bf16;
typedef __bf16 bf16x8 __attribute__((ext_vector_type(8)));
typedef float  f32x16 __attribute__((ext_vector_type(16)));

#define TAILF  13.815510557964274f      /* -log(1e-6) */
#define LOGZ   41.352233994210265f      /* 0.5*45*log(2*pi) */

// ---------------- workspace layout (bytes) ----------------
#define WS_W0M   0            /* bf16 [6][8 cg][4 kt][512]   196608 */
#define WS_WHM   196608       /* bf16 [12][8 cg][16 kt][512] 1572864 */
#define WS_WFM   1769472      /* bf16 [30][7 cg][16 kt][512] 3440640 */
#define WS_BEFF  5210112      /* f32  [6][256]   6144 */
#define WS_BFP   5216256      /* f32  [30][224]  26880 */
#define WS_WCC   5243136      /* f32  [6][256]   6144 */
#define WS_BHP   5249280      /* f32  [12][256]  12288 */
#define WS_NEED  5261568

#define N_W0  (6*256*64)        /* 98304   */
#define N_WH  (6*2*256*256)     /* 786432  */
#define N_WF  (6*5*224*256)     /* 1720320 */
#define N_PREP (N_W0 + N_WH + N_WF)

// ---- sorted-degree permutation of hidden units ----
// orig degree-1 of unit k is k%44.  Sorted position s -> degree-1 s_deg(s),
// original index s_orig(s).  Degrees 0..35 have 6 copies, 36..43 have 5.
__device__ __forceinline__ int s_deg(int s) {
    return (s < 216) ? (s / 6) : (36 + (s - 216) / 5);
}
__device__ __forceinline__ int s_orig(int s) {
    int d, rk;
    if (s < 216) { d = s / 6; rk = s - d * 6; }
    else { int u = s - 216; d = 36 + u / 5; rk = u - (u / 5) * 5; }
    return d + 44 * rk;
}

// ---------------- merged prep kernel (mask + permute + cast + pack) --------
__global__ void prep_all(const float* __restrict__ W0, const float* __restrict__ b0,
                         const float* __restrict__ Wc, const float* __restrict__ bc,
                         const float* __restrict__ Wh, const float* __restrict__ Wf,
                         const float* __restrict__ bfv, const float* __restrict__ bh,
                         bf16* __restrict__ W0m, bf16* __restrict__ Whm,
                         bf16* __restrict__ Wfm,
                         float* __restrict__ beff, float* __restrict__ bfp,
                         float* __restrict__ Wcc, float* __restrict__ bhp)
{
    int idx = blockIdx.x * 256 + threadIdx.x;
    if (idx < N_W0) {
        int j = idx & 7, lane = (idx >> 3) & 63, chunk = idx >> 9;
        int kt = chunk & 3, cg = (chunk >> 2) & 7, b = chunk >> 5;
        int col = cg * 32 + (lane & 31);               // sorted hidden pos
        int k   = kt * 16 + (lane >> 5) * 8 + j;
        int o   = s_orig(col);
        float v = 0.f;
        if (k < 45 && s_deg(col) >= k)                 // m0: deg_h >= k+1
            v = W0[(b * 256 + o) * 45 + k];
        W0m[idx] = (bf16)v;
        if (k == 0) {
            beff[b * 256 + col] = b0[b * 256 + o] + bc[b * 256 + o];
            Wcc[b * 256 + col]  = Wc[b * 256 + o];
        }
    } else if (idx < N_W0 + N_WH) {
        int id = idx - N_W0;
        int j = id & 7, lane = (id >> 3) & 63, chunk = id >> 9;
        int kt = chunk & 15, cg = (chunk >> 4) & 7, bl = chunk >> 7;  // bl=b*2+l
        int col = cg * 32 + (lane & 31);
        int k   = kt * 16 + (lane >> 5) * 8 + j;
        int oc  = s_orig(col), ok = s_orig(k);
        float v = (s_deg(col) >= s_deg(k)) ? Wh[bl * 65536 + oc * 256 + ok] : 0.f;
        Whm[id] = (bf16)v;
        if (k == 0)
            bhp[bl * 256 + col] = bh[bl * 256 + oc];
    } else if (idx < N_PREP) {
        int id = idx - (N_W0 + N_WH);
        int j = id & 7, lane = (id >> 3) & 63, chunk = id >> 9;
        int kt = chunk & 15, t2 = chunk >> 4;
        int cg = t2 % 7, bg = t2 / 7;                  // bg = b*5+g
        int b  = bg / 5, g = bg - 5 * b;
        int col = cg * 32 + (lane & 31);               // 0..223 (param col)
        int k   = kt * 16 + (lane >> 5) * 8 + j;
        int ok  = s_orig(k);
        int f   = 9 * g + col / 23;
        int m   = col - (col / 23) * 23;
        bool valid = (col < 207);
        float v = 0.f;
        if (valid && (f > s_deg(k)))                   // mf strict
            v = Wf[(b * 1035 + f * 23 + m) * 256 + ok];
        Wfm[id] = (bf16)v;
        if (k == 0)
            bfp[bg * 224 + col] = valid ? bfv[b * 1035 + f * 23 + m] : 0.f;
    }
}

// ---------------- fused main kernel ----------------
// LDS (dynamic, 81040 B -> 2 blocks/CU):
#define SO_ZF    0        /* float [64][46]          11776 */
#define SO_ZB    11776    /* bf16  [64][56]           7168 */
#define SO_HIDA  18944    /* bf16  [64][264]         33792 */
#define SO_PBUF  52736    /* bf16  9 x 1544 (fl-major, 24/row + 8 skew) 27792 */
#define SO_COND  80528    /* float [64] */
#define SO_LD    80784    /* float [64] */
#define SMEM_BYTES 81040

#define PBF 1544          /* elements per feature slab: 64*24 + 8 skew */

// K-tile counts (padded to x4; chunks beyond each mask prefix are zero in the
// packed buffers, so padding is numerically free).
__constant__ unsigned char HID_KT[8]    = {4,8,8,12,12,12,16,16};
__constant__ unsigned char OUT_KT[5][7] = {
    { 4, 4, 4, 4, 4, 4, 4},
    { 4, 8, 8, 8, 8, 8, 8},
    { 8, 8,12,12,12,12,12},
    {12,12,12,12,16,16,16},
    {16,16,16,16,16,16,16}};

// Epilogue for one 32x32 accumulator. C/D: col=lane&31, row=(r&3)+8*(r>>2)+4*(lane>>5).
// MODE 0: +bias+cond*wcol -> hidA; MODE 1: +bias, relu -> hidA;
// MODE 2: +bias -> pbuf (per-feature slab layout).
template<int MODE>
__device__ __forceinline__ void epi32(const f32x16& acc, int cg, int hf,
    const float* __restrict__ bias, const float* __restrict__ wcol,
    const float* condl, bf16* dst, int l31, int kh8)
{
    const int col = cg * 32 + l31;
    if (MODE == 2 && col >= 207) return;
    const float bv = bias[col];
    const int rb = (kh8 >> 1) + hf * 32;    // 4*(lane>>5) + half*32
    if (MODE == 2) {
        const int fl = col / 23, m = col - fl * 23;
        bf16* dp = dst + fl * PBF + m;
        #pragma unroll
        for (int r = 0; r < 16; ++r) {
            int row = (r & 3) + 8 * (r >> 2) + rb;
            dp[row * 24] = (bf16)(acc[r] + bv);
        }
    } else {
        const float wcv = (MODE == 0) ? wcol[col] : 0.f;
        #pragma unroll
        for (int r = 0; r < 16; ++r) {
            int row = (r & 3) + 8 * (r >> 2) + rb;
            float v = acc[r] + bv;
            if (MODE == 0) v += condl[row] * wcv;
            if (MODE == 1) v = fmaxf(v, 0.f);
            dst[row * 264 + col] = (bf16)v;
        }
    }
}

// GEMM: one cg per wave, BOTH row-halves (acc0 rows 0-31, acc1 rows 32-63)
// sharing each 1KB B-chunk. kt multiple of 4. Straight-line pipelined code:
// preload 2 quads of B, then prefetch quad q+1 while computing quad q.
// halfmask selects which halves get written at the epilogue.
template<int KTFULL, int MODE>
__device__ __forceinline__ void gemm64(
    const bf16* Asrc, const int lda,
    const bf16* __restrict__ Wp,
    const float* __restrict__ bias, const float* __restrict__ wcol,
    const float* condl, bf16* dst,
    int cg, int kt, int halfmask,
    int lane, bool preEpiSync)
{
    const int l31 = lane & 31;
    const int kh8 = (lane >> 5) * 8;
    const bf16* Bp  = Wp + (size_t)cg * (KTFULL * 512) + lane * 8;
    const bf16* Alo = Asrc + l31 * lda + kh8;
    const bf16* Ahi = Alo + 32 * lda;

    f32x16 acc0 = {}, acc1 = {};
    bf16x8 pA0, pA1, pA2, pA3, pB0, pB1, pB2, pB3;

#define LB(c)  (*reinterpret_cast<const bf16x8*>(Bp + (c) * 512))
#define LAL(c) (*reinterpret_cast<const bf16x8*>(Alo + (c) * 16))
#define LAH(c) (*reinterpret_cast<const bf16x8*>(Ahi + (c) * 16))
#define CHUNK(breg, c) { \
    bf16x8 a0_ = LAL(c), a1_ = LAH(c); \
    acc0 = __builtin_amdgcn_mfma_f32_32x32x16_bf16(a0_, breg, acc0, 0, 0, 0); \
    acc1 = __builtin_amdgcn_mfma_f32_32x32x16_bf16(a1_, breg, acc1, 0, 0, 0); }
#define LOADQ(r0, r1, r2, r3, q) { \
    r0 = LB((q)*4 + 0); r1 = LB((q)*4 + 1); \
    r2 = LB((q)*4 + 2); r3 = LB((q)*4 + 3); }
#define COMPQ(r0, r1, r2, r3, q) { \
    CHUNK(r0, (q)*4 + 0) CHUNK(r1, (q)*4 + 1) \
    CHUNK(r2, (q)*4 + 2) CHUNK(r3, (q)*4 + 3) }

    const int nq = __builtin_amdgcn_readfirstlane(kt >> 2);
    switch (nq) {
    case 1:
        LOADQ(pA0,pA1,pA2,pA3, 0);
        COMPQ(pA0,pA1,pA2,pA3, 0);
        break;
    case 2:
        LOADQ(pA0,pA1,pA2,pA3, 0); LOADQ(pB0,pB1,pB2,pB3, 1);
        COMPQ(pA0,pA1,pA2,pA3, 0); COMPQ(pB0,pB1,pB2,pB3, 1);
        break;
    case 3:
        LOADQ(pA0,pA1,pA2,pA3, 0); LOADQ(pB0,pB1,pB2,pB3, 1);
        COMPQ(pA0,pA1,pA2,pA3, 0); LOADQ(pA0,pA1,pA2,pA3, 2);
        COMPQ(pB0,pB1,pB2,pB3, 1); COMPQ(pA0,pA1,pA2,pA3, 2);
        break;
    default:
        LOADQ(pA0,pA1,pA2,pA3, 0); LOADQ(pB0,pB1,pB2,pB3, 1);
        COMPQ(pA0,pA1,pA2,pA3, 0); LOADQ(pA0,pA1,pA2,pA3, 2);
        COMPQ(pB0,pB1,pB2,pB3, 1); LOADQ(pB0,pB1,pB2,pB3, 3);
        COMPQ(pA0,pA1,pA2,pA3, 2); COMPQ(pB0,pB1,pB2,pB3, 3);
        break;
    }
#undef LB
#undef LAL
#undef LAH
#undef CHUNK
#undef LOADQ
#undef COMPQ

    if (preEpiSync) __syncthreads();   // in-place layers: all A reads done

    if (halfmask & 1) epi32<MODE>(acc0, cg, 0, bias, wcol, condl, dst, l31, kh8);
    if (halfmask & 2) epi32<MODE>(acc1, cg, 1, bias, wcol, condl, dst, l31, kh8);
    __syncthreads();
}

// RQ spline for 9 features starting at fb. Task map: fl = task>>6 (wave-
// uniform), r = task&63 -> fixed row per thread; log-det accumulates in reg.
__device__ __forceinline__ void do_spline9(int fb, float* zf, bf16* zb,
                                           const bf16* pbuf, int t, float& lad_acc)
{
    #pragma unroll 1
    for (int task = t; task < 576; task += 512) {
        int fl = task >> 6, r = task & 63;
        const bf16* pp = pbuf + fl * PBF + r * 24;
        bf16x8 q0 = *reinterpret_cast<const bf16x8*>(pp);
        bf16x8 q1 = *reinterpret_cast<const bf16x8*>(pp + 8);
        bf16x8 q2 = *reinterpret_cast<const bf16x8*>(pp + 16);
        float P[23];
        #pragma unroll
        for (int m = 0; m < 8; ++m) P[m]      = (float)q0[m];
        #pragma unroll
        for (int m = 0; m < 8; ++m) P[8 + m]  = (float)q1[m];
        #pragma unroll
        for (int m = 0; m < 7; ++m) P[16 + m] = (float)q2[m];

        float xin = zf[r * 46 + fb + fl];
        float xc  = fminf(fmaxf(xin, -TAILF), TAILF);
        bool inside = (xin >= -TAILF) && (xin <= TAILF);

        float mw = P[0];
        #pragma unroll
        for (int i = 1; i < 8; ++i) mw = fmaxf(mw, P[i]);
        float ew[8], sw = 0.f;
        #pragma unroll
        for (int i = 0; i < 8; ++i) { ew[i] = __expf((P[i] - mw) * 0.0625f); sw += ew[i]; }
        float rws = 0.992f / sw;
        float cw[9]; cw[0] = -TAILF;
        #pragma unroll
        for (int i = 0; i < 8; ++i)
            cw[i + 1] = cw[i] + 2.f * TAILF * (1e-3f + ew[i] * rws);
        cw[8] = TAILF;
        float wb[8];
        #pragma unroll
        for (int i = 0; i < 8; ++i) wb[i] = cw[i + 1] - cw[i];

        float mh = P[8];
        #pragma unroll
        for (int i = 1; i < 8; ++i) mh = fmaxf(mh, P[8 + i]);
        float eh[8], sh = 0.f;
        #pragma unroll
        for (int i = 0; i < 8; ++i) { eh[i] = __expf((P[8 + i] - mh) * 0.0625f); sh += eh[i]; }
        float rhs = 0.992f / sh;
        float ch[9]; ch[0] = -TAILF;
        #pragma unroll
        for (int i = 0; i < 8; ++i)
            ch[i + 1] = ch[i] + 2.f * TAILF * (1e-3f + eh[i] * rhs);
        ch[8] = TAILF;
        float hb[8];
        #pragma unroll
        for (int i = 0; i < 8; ++i) hb[i] = ch[i + 1] - ch[i];

        float dd[9];
        dd[0] = 1.0f; dd[8] = 1.0f;
        #pragma unroll
        for (int i = 1; i < 8; ++i)
            dd[i] = 1e-3f + __logf(1.f + __expf(P[15 + i]));

        float icw = cw[0], ich = ch[0], ibw = wb[0], ibh = hb[0];
        float id0 = dd[0], id1 = dd[1];
        #pragma unroll
        for (int i = 1; i < 8; ++i) {
            bool ge = xc >= cw[i];
            icw = ge ? cw[i] : icw;  ich = ge ? ch[i] : ich;
            ibw = ge ? wb[i] : ibw;  ibh = ge ? hb[i] : ibh;
            id0 = ge ? dd[i] : id0;  id1 = ge ? dd[i + 1] : id1;
        }

        float th  = (xc - icw) / ibw;
        float th1 = th * (1.f - th);
        float dl  = ibh / ibw;
        float den = dl + (id0 + id1 - 2.f * dl) * th1;
        float yy  = ich + ibh * (dl * th * th + id0 * th1) / den;
        float num = dl * dl * (id1 * th * th + 2.f * dl * th1
                               + id0 * (1.f - th) * (1.f - th));
        float lad = __logf(num) - 2.f * __logf(den);

        if (inside) {
            zf[r * 46 + fb + fl] = yy;
            zb[r * 56 + fb + fl] = (bf16)yy;
        }
        lad_acc += inside ? lad : 0.f;
    }
}

__global__ __launch_bounds__(512, 4) void maf_main(
    const float* __restrict__ x, const float* __restrict__ cond,
    const bf16* __restrict__ W0m, const bf16* __restrict__ Whm,
    const bf16* __restrict__ Wfm,
    const float* __restrict__ beff, const float* __restrict__ bfp,
    const float* __restrict__ Wcc, const float* __restrict__ bhp,
    float* __restrict__ out, int B)
{
    extern __shared__ char smem[];
    float* zf    = (float*)(smem + SO_ZF);
    bf16*  zb    = (bf16*)(smem + SO_ZB);
    bf16*  hidA  = (bf16*)(smem + SO_HIDA);
    bf16*  pbuf  = (bf16*)(smem + SO_PBUF);
    float* condl = (float*)(smem + SO_COND);
    float* ldl   = (float*)(smem + SO_LD);

    const int t    = threadIdx.x;
    const int r0   = blockIdx.x * 64;
    const int w    = t >> 6;
    const int lane = t & 63;
    const int wu   = __builtin_amdgcn_readfirstlane(w);

    for (int i = t; i < 64 * 11; i += 512) {
        int r = i / 11, c = i - (i / 11) * 11;
        zb[r * 56 + 45 + c] = (bf16)0.f;
    }
    for (int i = t; i < 64 * 45; i += 512) {
        int r = i / 45, f = i - (i / 45) * 45;
        float v = (r0 + r < B) ? x[(size_t)(r0 + r) * 45 + f] : 0.f;
        zf[r * 46 + f] = v;
        zb[r * 56 + f] = (bf16)v;
    }
    if (t < 64) {
        condl[t] = (r0 + t < B) ? cond[r0 + t] : 0.f;
        ldl[t]   = 0.f;
    }
    __syncthreads();

    float lad_acc = 0.f;

    const int hidKt = HID_KT[wu];
    const int ocg   = (wu <= 5) ? wu : 6;                 // output col-group
    const int ohm   = (wu <= 5) ? 3 : ((wu == 6) ? 1 : 2); // output halfmask

    #pragma unroll 1
    for (int b = 0; b < 6; ++b) {
        // input MADE layer (kt=4 covers padded K=64), +cond*Wc + (b0+bc)
        gemm64<4, 0>(zb, 56, W0m + b * 16384,
                     beff + b * 256, Wcc + b * 256, condl,
                     hidA, wu, 4, 3, lane, false);
        // 2 hidden layers, relu, in-place
        #pragma unroll 1
        for (int l = 0; l < 2; ++l)
            gemm64<16, 1>(hidA, 264, Whm + (b * 2 + l) * 65536,
                          bhp + (b * 2 + l) * 256, nullptr, condl,
                          hidA, wu, hidKt, 3, lane, true);
        // params: 5 groups x 9 features (207 real cols of 224)
        #pragma unroll 1
        for (int g = 0; g < 5; ++g) {
            gemm64<16, 2>(hidA, 264, Wfm + (size_t)(b * 5 + g) * 57344,
                          bfp + (b * 5 + g) * 224, nullptr, condl,
                          pbuf, ocg, OUT_KT[g][ocg], ohm, lane, false);
            do_spline9(g * 9, zf, zb, pbuf, t, lad_acc);
            __syncthreads();
        }
    }

    atomicAdd(&ldl[t & 63], lad_acc);
    __syncthreads();

    if (t < 64 && r0 + t < B) {
        float s = 0.f;
        #pragma unroll
        for (int f = 0; f < 45; ++f) { float v = zf[t * 46 + f]; s += v * v; }
        out[r0 + t] = -0.5f * s - LOGZ + ldl[t];
    }
}

// ---------------- host entry ----------------
extern "C" void kernel_launch(void* const* d_in, const int* in_sizes, int n_in,
                              void* d_out, int out_size, void* d_ws, size_t ws_size,
                              hipStream_t stream)
{
    const float* x    = (const float*)d_in[0];
    const float* cond = (const float*)d_in[1];
    const float* W0   = (const float*)d_in[2];
    const float* b0   = (const float*)d_in[3];
    const float* Wc   = (const float*)d_in[4];
    const float* bc   = (const float*)d_in[5];
    const float* Wh   = (const float*)d_in[6];
    const float* bh   = (const float*)d_in[7];
    const float* Wf   = (const float*)d_in[8];
    const float* bfv  = (const float*)d_in[9];
    float* out = (float*)d_out;

    const int B = in_sizes[0] / 45;
    if (ws_size < (size_t)WS_NEED) return;   // fail loudly

    char* ws = (char*)d_ws;
    bf16*  W0m  = (bf16*)(ws + WS_W0M);
    bf16*  Whm  = (bf16*)(ws + WS_WHM);
    bf16*  Wfm  = (bf16*)(ws + WS_WFM);
    float* beff = (float*)(ws + WS_BEFF);
    float* bfp  = (float*)(ws + WS_BFP);
    float* Wcc  = (float*)(ws + WS_WCC);
    float* bhp  = (float*)(ws + WS_BHP);

    prep_all<<<(N_PREP + 255) / 256, 256, 0, stream>>>(
        W0, b0, Wc, bc, Wh, Wf, bfv, bh, W0m, Whm, Wfm, beff, bfp, Wcc, bhp);

    (void)hipFuncSetAttribute((const void*)maf_main,
                              hipFuncAttributeMaxDynamicSharedMemorySize,
                              SMEM_BYTES);

    const int nwg = (B + 63) / 64;
    maf_main<<<nwg, 512, SMEM_BYTES, stream>>>(
        x, cond, W0m, Whm, Wfm, beff, bfp, Wcc, bhp, out, B);
}

// Round 5
// 320.767 us; speedup vs baseline: 1.1625x; 1.0151x over previous
//
#include <hip/hip_runtime.h>

// ---------------------------------------------------------------------------
// MAF forward log-prob, fully fused. D=45, H=256, NB=6, L=2, K=8, M=23.
// R7: R6's features with de-risked codegen. (1) pair-granularity K-prefixes,
// now a ROLLED pipelined loop (ping-pong reg pairs, prefetch distance 2,
// uniform trip count) instead of an 8-case straight-line switch; (2) spline
// (g-1) runs inside output-gemm(g) between B-load issue and MFMA via
// template<bool SPLINE> (no lambda); (3) per-cg input prefixes. One cg per
// wave, both row-halves share each 1KB B chunk. 512 thr/WG, ~79 KiB LDS,
// 2 WGs/CU.
// ---------------------------------------------------------------------------

typedef __bf16 bf16;
typedef __bf16 bf16x8 __attribute__((ext_vector_type(8)));
typedef float  f32x16 __attribute__((ext_vector_type(16)));

#define TAILF  13.815510557964274f      /* -log(1e-6) */
#define LOGZ   41.352233994210265f      /* 0.5*45*log(2*pi) */

// ---------------- workspace layout (bytes) ----------------
#define WS_W0M   0            /* bf16 [6][8 cg][4 kt][512]   196608 */
#define WS_WHM   196608       /* bf16 [12][8 cg][16 kt][512] 1572864 */
#define WS_WFM   1769472      /* bf16 [30][7 cg][16 kt][512] 3440640 */
#define WS_BEFF  5210112      /* f32  [6][256]   6144 */
#define WS_BFP   5216256      /* f32  [30][224]  26880 */
#define WS_WCC   5243136      /* f32  [6][256]   6144 */
#define WS_BHP   5249280      /* f32  [12][256]  12288 */
#define WS_NEED  5261568

#define N_W0  (6*256*64)        /* 98304   */
#define N_WH  (6*2*256*256)     /* 786432  */
#define N_WF  (6*5*224*256)     /* 1720320 */
#define N_PREP (N_W0 + N_WH + N_WF)

// ---- sorted-degree permutation of hidden units ----
// orig degree-1 of unit k is k%44.  Sorted position s -> degree-1 s_deg(s),
// original index s_orig(s).  Degrees 0..35 have 6 copies, 36..43 have 5.
__device__ __forceinline__ int s_deg(int s) {
    return (s < 216) ? (s / 6) : (36 + (s - 216) / 5);
}
__device__ __forceinline__ int s_orig(int s) {
    int d, rk;
    if (s < 216) { d = s / 6; rk = s - d * 6; }
    else { int u = s - 216; d = 36 + u / 5; rk = u - (u / 5) * 5; }
    return d + 44 * rk;
}

// ---------------- merged prep kernel (mask + permute + cast + pack) --------
__global__ void prep_all(const float* __restrict__ W0, const float* __restrict__ b0,
                         const float* __restrict__ Wc, const float* __restrict__ bc,
                         const float* __restrict__ Wh, const float* __restrict__ Wf,
                         const float* __restrict__ bfv, const float* __restrict__ bh,
                         bf16* __restrict__ W0m, bf16* __restrict__ Whm,
                         bf16* __restrict__ Wfm,
                         float* __restrict__ beff, float* __restrict__ bfp,
                         float* __restrict__ Wcc, float* __restrict__ bhp)
{
    int idx = blockIdx.x * 256 + threadIdx.x;
    if (idx < N_W0) {
        int j = idx & 7, lane = (idx >> 3) & 63, chunk = idx >> 9;
        int kt = chunk & 3, cg = (chunk >> 2) & 7, b = chunk >> 5;
        int col = cg * 32 + (lane & 31);               // sorted hidden pos
        int k   = kt * 16 + (lane >> 5) * 8 + j;
        int o   = s_orig(col);
        float v = 0.f;
        if (k < 45 && s_deg(col) >= k)                 // m0: deg_h >= k+1
            v = W0[(b * 256 + o) * 45 + k];
        W0m[idx] = (bf16)v;
        if (k == 0) {
            beff[b * 256 + col] = b0[b * 256 + o] + bc[b * 256 + o];
            Wcc[b * 256 + col]  = Wc[b * 256 + o];
        }
    } else if (idx < N_W0 + N_WH) {
        int id = idx - N_W0;
        int j = id & 7, lane = (id >> 3) & 63, chunk = id >> 9;
        int kt = chunk & 15, cg = (chunk >> 4) & 7, bl = chunk >> 7;  // bl=b*2+l
        int col = cg * 32 + (lane & 31);
        int k   = kt * 16 + (lane >> 5) * 8 + j;
        int oc  = s_orig(col), ok = s_orig(k);
        float v = (s_deg(col) >= s_deg(k)) ? Wh[bl * 65536 + oc * 256 + ok] : 0.f;
        Whm[id] = (bf16)v;
        if (k == 0)
            bhp[bl * 256 + col] = bh[bl * 256 + oc];
    } else if (idx < N_PREP) {
        int id = idx - (N_W0 + N_WH);
        int j = id & 7, lane = (id >> 3) & 63, chunk = id >> 9;
        int kt = chunk & 15, t2 = chunk >> 4;
        int cg = t2 % 7, bg = t2 / 7;                  // bg = b*5+g
        int b  = bg / 5, g = bg - 5 * b;
        int col = cg * 32 + (lane & 31);               // 0..223 (param col)
        int k   = kt * 16 + (lane >> 5) * 8 + j;
        int ok  = s_orig(k);
        int f   = 9 * g + col / 23;
        int m   = col - (col / 23) * 23;
        bool valid = (col < 207);
        float v = 0.f;
        if (valid && (f > s_deg(k)))                   // mf strict
            v = Wf[(b * 1035 + f * 23 + m) * 256 + ok];
        Wfm[id] = (bf16)v;
        if (k == 0)
            bfp[bg * 224 + col] = valid ? bfv[b * 1035 + f * 23 + m] : 0.f;
    }
}

// ---------------- fused main kernel ----------------
// LDS (dynamic, 81040 B -> 2 blocks/CU):
#define SO_ZF    0        /* float [64][46]          11776 */
#define SO_ZB    11776    /* bf16  [64][56]           7168 */
#define SO_HIDA  18944    /* bf16  [64][264]         33792 */
#define SO_PBUF  52736    /* bf16  9 x 1544 (fl-major, 24/row + 8 skew) 27792 */
#define SO_COND  80528    /* float [64] */
#define SO_LD    80784    /* float [64] */
#define SMEM_BYTES 81040

#define PBF 1544          /* elements per feature slab: 64*24 + 8 skew */

// Chunk-PAIR counts per wave (np = ceil(real_prefix_chunks / 2)).
// Chunks beyond each mask prefix are zero in the packed buffers, so the
// rounding-up to a pair is numerically free.
__constant__ unsigned char IN_NP[8]     = {1,1,1,1,1,1,2,2};
__constant__ unsigned char HID_NP[8]    = {2,3,3,5,6,6,8,8};
__constant__ unsigned char OUT_NP[5][7] = {
    {1,1,1,1,2,2,2},
    {2,3,3,3,3,4,4},
    {4,4,5,5,5,5,5},
    {6,6,6,6,7,7,7},
    {7,8,8,8,8,8,8}};

// forward decl
__device__ __forceinline__ void do_spline9(int fb, float* zf, bf16* zb,
                                           const bf16* pbuf, int t, float& lad_acc);

// Epilogue for one 32x32 accumulator. C/D: col=lane&31, row=(r&3)+8*(r>>2)+4*(lane>>5).
// MODE 0: +bias+cond*wcol -> hidA; MODE 1: +bias, relu -> hidA;
// MODE 2: +bias -> pbuf (per-feature slab layout).
template<int MODE>
__device__ __forceinline__ void epi32(const f32x16& acc, int cg, int hf,
    const float* __restrict__ bias, const float* __restrict__ wcol,
    const float* condl, bf16* dst, int l31, int kh8)
{
    const int col = cg * 32 + l31;
    if (MODE == 2 && col >= 207) return;
    const float bv = bias[col];
    const int rb = (kh8 >> 1) + hf * 32;    // 4*(lane>>5) + half*32
    if (MODE == 2) {
        const int fl = col / 23, m = col - fl * 23;
        bf16* dp = dst + fl * PBF + m;
        #pragma unroll
        for (int r = 0; r < 16; ++r) {
            int row = (r & 3) + 8 * (r >> 2) + rb;
            dp[row * 24] = (bf16)(acc[r] + bv);
        }
    } else {
        const float wcv = (MODE == 0) ? wcol[col] : 0.f;
        #pragma unroll
        for (int r = 0; r < 16; ++r) {
            int row = (r & 3) + 8 * (r >> 2) + rb;
            float v = acc[r] + bv;
            if (MODE == 0) v += condl[row] * wcv;
            if (MODE == 1) v = fmaxf(v, 0.f);
            dst[row * 264 + col] = (bf16)v;
        }
    }
}

// GEMM: one cg per wave, BOTH row-halves (acc0 rows 0-31, acc1 rows 32-63)
// sharing each 1KB B-chunk. np = number of chunk PAIRS (wave-uniform).
// Rolled pipeline: preload pairs 0,1 into ping-pong regs; optional spline
// overlap fills the load-latency window; loop computes pair p while
// prefetching pair p+2 (distance-2-pair). Uniform branches only.
template<int KTFULL, int MODE, bool SPLINE>
__device__ __forceinline__ void gemm64(
    const bf16* Asrc, const int lda,
    const bf16* __restrict__ Wp,
    const float* __restrict__ bias, const float* __restrict__ wcol,
    const float* condl, bf16* dst,
    int cg, int np, int halfmask,
    int lane, bool preEpiSync,
    int fb, float* zf, bf16* zb, const bf16* pbuf, int t, float* lad_acc)
{
    const int l31 = lane & 31;
    const int kh8 = (lane >> 5) * 8;
    const bf16* Bp  = Wp + (size_t)cg * (KTFULL * 512) + lane * 8;
    const bf16* Alo = Asrc + l31 * lda + kh8;
    const bf16* Ahi = Alo + 32 * lda;

    f32x16 acc0 = {}, acc1 = {};
    bf16x8 rA0, rA1, rB0, rB1;

#define LB(c)  (*reinterpret_cast<const bf16x8*>(Bp + (size_t)(c) * 512))
#define LAL(c) (*reinterpret_cast<const bf16x8*>(Alo + (c) * 16))
#define LAH(c) (*reinterpret_cast<const bf16x8*>(Ahi + (c) * 16))
#define CHUNK(breg, c) { \
    bf16x8 a0_ = LAL(c), a1_ = LAH(c); \
    acc0 = __builtin_amdgcn_mfma_f32_32x32x16_bf16(a0_, breg, acc0, 0, 0, 0); \
    acc1 = __builtin_amdgcn_mfma_f32_32x32x16_bf16(a1_, breg, acc1, 0, 0, 0); }
#define LP(r0, r1, p) { r0 = LB(2*(p)); r1 = LB(2*(p)+1); }
#define CP(r0, r1, p) { CHUNK(r0, 2*(p)) CHUNK(r1, 2*(p)+1) }

    LP(rA0, rA1, 0);
    if (np > 1) LP(rB0, rB1, 1);

    if constexpr (SPLINE)                  // hides B-load latency
        do_spline9(fb, zf, zb, pbuf, t, *lad_acc);

    int p = 0;
    #pragma unroll 1
    while (p + 2 < np) {
        CP(rA0, rA1, p);
        LP(rA0, rA1, p + 2);
        CP(rB0, rB1, p + 1);
        if (p + 3 < np) LP(rB0, rB1, p + 3);
        p += 2;
    }
    CP(rA0, rA1, p);
    if (np - p > 1) CP(rB0, rB1, p + 1);

#undef LB
#undef LAL
#undef LAH
#undef CHUNK
#undef LP
#undef CP

    if (preEpiSync) __syncthreads();   // in-place layers / pbuf reuse

    if (halfmask & 1) epi32<MODE>(acc0, cg, 0, bias, wcol, condl, dst, l31, kh8);
    if (halfmask & 2) epi32<MODE>(acc1, cg, 1, bias, wcol, condl, dst, l31, kh8);
    __syncthreads();
}

// RQ spline for 9 features starting at fb. Task map: fl = task>>6 (wave-
// uniform), r = task&63 -> fixed row per thread; log-det accumulates in reg.
__device__ __forceinline__ void do_spline9(int fb, float* zf, bf16* zb,
                                           const bf16* pbuf, int t, float& lad_acc)
{
    #pragma unroll 1
    for (int task = t; task < 576; task += 512) {
        int fl = task >> 6, r = task & 63;
        const bf16* pp = pbuf + fl * PBF + r * 24;
        bf16x8 q0 = *reinterpret_cast<const bf16x8*>(pp);
        bf16x8 q1 = *reinterpret_cast<const bf16x8*>(pp + 8);
        bf16x8 q2 = *reinterpret_cast<const bf16x8*>(pp + 16);
        float P[23];
        #pragma unroll
        for (int m = 0; m < 8; ++m) P[m]      = (float)q0[m];
        #pragma unroll
        for (int m = 0; m < 8; ++m) P[8 + m]  = (float)q1[m];
        #pragma unroll
        for (int m = 0; m < 7; ++m) P[16 + m] = (float)q2[m];

        float xin = zf[r * 46 + fb + fl];
        float xc  = fminf(fmaxf(xin, -TAILF), TAILF);
        bool inside = (xin >= -TAILF) && (xin <= TAILF);

        float mw = P[0];
        #pragma unroll
        for (int i = 1; i < 8; ++i) mw = fmaxf(mw, P[i]);
        float ew[8], sw = 0.f;
        #pragma unroll
        for (int i = 0; i < 8; ++i) { ew[i] = __expf((P[i] - mw) * 0.0625f); sw += ew[i]; }
        float rws = 0.992f / sw;
        float cw[9]; cw[0] = -TAILF;
        #pragma unroll
        for (int i = 0; i < 8; ++i)
            cw[i + 1] = cw[i] + 2.f * TAILF * (1e-3f + ew[i] * rws);
        cw[8] = TAILF;
        float wb[8];
        #pragma unroll
        for (int i = 0; i < 8; ++i) wb[i] = cw[i + 1] - cw[i];

        float mh = P[8];
        #pragma unroll
        for (int i = 1; i < 8; ++i) mh = fmaxf(mh, P[8 + i]);
        float eh[8], sh = 0.f;
        #pragma unroll
        for (int i = 0; i < 8; ++i) { eh[i] = __expf((P[8 + i] - mh) * 0.0625f); sh += eh[i]; }
        float rhs = 0.992f / sh;
        float ch[9]; ch[0] = -TAILF;
        #pragma unroll
        for (int i = 0; i < 8; ++i)
            ch[i + 1] = ch[i] + 2.f * TAILF * (1e-3f + eh[i] * rhs);
        ch[8] = TAILF;
        float hb[8];
        #pragma unroll
        for (int i = 0; i < 8; ++i) hb[i] = ch[i + 1] - ch[i];

        float dd[9];
        dd[0] = 1.0f; dd[8] = 1.0f;
        #pragma unroll
        for (int i = 1; i < 8; ++i)
            dd[i] = 1e-3f + __logf(1.f + __expf(P[15 + i]));

        float icw = cw[0], ich = ch[0], ibw = wb[0], ibh = hb[0];
        float id0 = dd[0], id1 = dd[1];
        #pragma unroll
        for (int i = 1; i < 8; ++i) {
            bool ge = xc >= cw[i];
            icw = ge ? cw[i] : icw;  ich = ge ? ch[i] : ich;
            ibw = ge ? wb[i] : ibw;  ibh = ge ? hb[i] : ibh;
            id0 = ge ? dd[i] : id0;  id1 = ge ? dd[i + 1] : id1;
        }

        float th  = (xc - icw) / ibw;
        float th1 = th * (1.f - th);
        float dl  = ibh / ibw;
        float den = dl + (id0 + id1 - 2.f * dl) * th1;
        float yy  = ich + ibh * (dl * th * th + id0 * th1) / den;
        float num = dl * dl * (id1 * th * th + 2.f * dl * th1
                               + id0 * (1.f - th) * (1.f - th));
        float lad = __logf(num) - 2.f * __logf(den);

        if (inside) {
            zf[r * 46 + fb + fl] = yy;
            zb[r * 56 + fb + fl] = (bf16)yy;
        }
        lad_acc += inside ? lad : 0.f;
    }
}

__global__ __launch_bounds__(512, 4) void maf_main(
    const float* __restrict__ x, const float* __restrict__ cond,
    const bf16* __restrict__ W0m, const bf16* __restrict__ Whm,
    const bf16* __restrict__ Wfm,
    const float* __restrict__ beff, const float* __restrict__ bfp,
    const float* __restrict__ Wcc, const float* __restrict__ bhp,
    float* __restrict__ out, int B)
{
    extern __shared__ char smem[];
    float* zf    = (float*)(smem + SO_ZF);
    bf16*  zb    = (bf16*)(smem + SO_ZB);
    bf16*  hidA  = (bf16*)(smem + SO_HIDA);
    bf16*  pbuf  = (bf16*)(smem + SO_PBUF);
    float* condl = (float*)(smem + SO_COND);
    float* ldl   = (float*)(smem + SO_LD);

    const int t    = threadIdx.x;
    const int r0   = blockIdx.x * 64;
    const int w    = t >> 6;
    const int lane = t & 63;
    const int wu   = __builtin_amdgcn_readfirstlane(w);

    for (int i = t; i < 64 * 11; i += 512) {
        int r = i / 11, c = i - (i / 11) * 11;
        zb[r * 56 + 45 + c] = (bf16)0.f;
    }
    if (t < 8) hidA[t] = (bf16)0.f;   // zb row63 chunk-3 hi-half overreads here
    for (int i = t; i < 64 * 45; i += 512) {
        int r = i / 45, f = i - (i / 45) * 45;
        float v = (r0 + r < B) ? x[(size_t)(r0 + r) * 45 + f] : 0.f;
        zf[r * 46 + f] = v;
        zb[r * 56 + f] = (bf16)v;
    }
    if (t < 64) {
        condl[t] = (r0 + t < B) ? cond[r0 + t] : 0.f;
        ldl[t]   = 0.f;
    }
    __syncthreads();

    float lad_acc = 0.f;

    const int inNp  = IN_NP[wu];
    const int hidNp = HID_NP[wu];
    const int ocg   = (wu <= 5) ? wu : 6;                 // output col-group
    const int ohm   = (wu <= 5) ? 3 : ((wu == 6) ? 1 : 2); // output halfmask

    #pragma unroll 1
    for (int b = 0; b < 6; ++b) {
        // input MADE layer (per-cg K prefix), +cond*Wc + (b0+bc)
        gemm64<4, 0, false>(zb, 56, W0m + b * 16384,
                            beff + b * 256, Wcc + b * 256, condl,
                            hidA, wu, inNp, 3, lane, false,
                            0, nullptr, nullptr, nullptr, 0, nullptr);
        // 2 hidden layers, relu, in-place
        #pragma unroll 1
        for (int l = 0; l < 2; ++l)
            gemm64<16, 1, false>(hidA, 264, Whm + (b * 2 + l) * 65536,
                                 bhp + (b * 2 + l) * 256, nullptr, condl,
                                 hidA, wu, hidNp, 3, lane, true,
                                 0, nullptr, nullptr, nullptr, 0, nullptr);
        // params: 5 groups x 9 features; spline(g-1) overlapped into gemm(g)
        gemm64<16, 2, false>(hidA, 264, Wfm + (size_t)(b * 5) * 57344,
                             bfp + (b * 5) * 224, nullptr, condl,
                             pbuf, ocg, OUT_NP[0][ocg], ohm, lane, false,
                             0, nullptr, nullptr, nullptr, 0, nullptr);
        #pragma unroll 1
        for (int g = 1; g < 5; ++g) {
            gemm64<16, 2, true>(hidA, 264, Wfm + (size_t)(b * 5 + g) * 57344,
                                bfp + (b * 5 + g) * 224, nullptr, condl,
                                pbuf, ocg, OUT_NP[g][ocg], ohm, lane, true,
                                (g - 1) * 9, zf, zb, pbuf, t, &lad_acc);
        }
        do_spline9(36, zf, zb, pbuf, t, lad_acc);
        __syncthreads();
    }

    atomicAdd(&ldl[t & 63], lad_acc);
    __syncthreads();

    if (t < 64 && r0 + t < B) {
        float s = 0.f;
        #pragma unroll
        for (int f = 0; f < 45; ++f) { float v = zf[t * 46 + f]; s += v * v; }
        out[r0 + t] = -0.5f * s - LOGZ + ldl[t];
    }
}

// ---------------- host entry ----------------
extern "C" void kernel_launch(void* const* d_in, const int* in_sizes, int n_in,
                              void* d_out, int out_size, void* d_ws, size_t ws_size,
                              hipStream_t stream)
{
    const float* x    = (const float*)d_in[0];
    const float* cond = (const float*)d_in[1];
    const float* W0   = (const float*)d_in[2];
    const float* b0   = (const float*)d_in[3];
    const float* Wc   = (const float*)d_in[4];
    const float* bc   = (const float*)d_in[5];
    const float* Wh   = (const float*)d_in[6];
    const float* bh   = (const float*)d_in[7];
    const float* Wf   = (const float*)d_in[8];
    const float* bfv  = (const float*)d_in[9];
    float* out = (float*)d_out;

    const int B = in_sizes[0] / 45;
    if (ws_size < (size_t)WS_NEED) return;   // fail loudly

    char* ws = (char*)d_ws;
    bf16*  W0m  = (bf16*)(ws + WS_W0M);
    bf16*  Whm  = (bf16*)(ws + WS_WHM);
    bf16*  Wfm  = (bf16*)(ws + WS_WFM);
    float* beff = (float*)(ws + WS_BEFF);
    float* bfp  = (float*)(ws + WS_BFP);
    float* Wcc  = (float*)(ws + WS_WCC);
    float* bhp  = (float*)(ws + WS_BHP);

    prep_all<<<(N_PREP + 255) / 256, 256, 0, stream>>>(
        W0, b0, Wc, bc, Wh, Wf, bfv, bh, W0m, Whm, Wfm, beff, bfp, Wcc, bhp);

    (void)hipFuncSetAttribute((const void*)maf_main,
                              hipFuncAttributeMaxDynamicSharedMemorySize,
                              SMEM_BYTES);

    const int nwg = (B + 63) / 64;
    maf_main<<<nwg, 512, SMEM_BYTES, stream>>>(
        x, cond, W0m, Whm, Wfm, beff, bfp, Wcc, bhp, out, B);
}